// Round 3
// baseline (15.989 us; speedup 1.0000x reference)
//
#include <hip/hip_runtime.h>
#include <hip/hip_bf16.h>

// out[i] = b + sum_{k=0..7} (w[k]/k!) * X[i]^k   — Horner, float4-vectorized.
// Memory-bound: 67 MB total traffic at N=8388608 → ~10.2 us floor @ 6.6 TB/s.
// Static 4x unroll: 4 independent 16B loads in flight per thread before any
// compute (MLP), nontemporal hints (pure streaming, zero reuse).
// Note: __builtin_nontemporal_* needs a clang native vector type, not HIP's
// struct float4 — use ext_vector_type(4).

typedef float f32x4 __attribute__((ext_vector_type(4)));

#define UNROLL 4

__device__ __forceinline__ float horner8(float x, float c0, float c1, float c2,
                                         float c3, float c4, float c5, float c6,
                                         float c7) {
    float r = fmaf(c7, x, c6);
    r = fmaf(r, x, c5);
    r = fmaf(r, x, c4);
    r = fmaf(r, x, c3);
    r = fmaf(r, x, c2);
    r = fmaf(r, x, c1);
    r = fmaf(r, x, c0);
    return r;
}

__global__ __launch_bounds__(256) void PolyModel_poly_fast(
    const f32x4* __restrict__ X,
    const float* __restrict__ w,
    const float* __restrict__ b,
    f32x4* __restrict__ out,
    int stride)   // threads in grid = n4 / UNROLL
{
    const float c0 = w[0] + b[0];
    const float c1 = w[1];
    const float c2 = w[2] * 0.5f;
    const float c3 = w[3] * (1.0f / 6.0f);
    const float c4 = w[4] * (1.0f / 24.0f);
    const float c5 = w[5] * (1.0f / 120.0f);
    const float c6 = w[6] * (1.0f / 720.0f);
    const float c7 = w[7] * (1.0f / 5040.0f);

    const int tid = blockIdx.x * blockDim.x + threadIdx.x;

    f32x4 x[UNROLL];
#pragma unroll
    for (int u = 0; u < UNROLL; ++u)
        x[u] = __builtin_nontemporal_load(&X[tid + u * stride]);

#pragma unroll
    for (int u = 0; u < UNROLL; ++u) {
        f32x4 r;
        r.x = horner8(x[u].x, c0, c1, c2, c3, c4, c5, c6, c7);
        r.y = horner8(x[u].y, c0, c1, c2, c3, c4, c5, c6, c7);
        r.z = horner8(x[u].z, c0, c1, c2, c3, c4, c5, c6, c7);
        r.w = horner8(x[u].w, c0, c1, c2, c3, c4, c5, c6, c7);
        __builtin_nontemporal_store(r, &out[tid + u * stride]);
    }
}

// Generic fallback (any n divisible by 4) — grid-stride Horner.
__global__ __launch_bounds__(256) void PolyModel_poly_generic(
    const f32x4* __restrict__ X,
    const float* __restrict__ w,
    const float* __restrict__ b,
    f32x4* __restrict__ out,
    int n4)
{
    const float c0 = w[0] + b[0];
    const float c1 = w[1];
    const float c2 = w[2] * 0.5f;
    const float c3 = w[3] * (1.0f / 6.0f);
    const float c4 = w[4] * (1.0f / 24.0f);
    const float c5 = w[5] * (1.0f / 120.0f);
    const float c6 = w[6] * (1.0f / 720.0f);
    const float c7 = w[7] * (1.0f / 5040.0f);

    const int stride = gridDim.x * blockDim.x;
    for (int i = blockIdx.x * blockDim.x + threadIdx.x; i < n4; i += stride) {
        f32x4 x = X[i];
        f32x4 r;
        r.x = horner8(x.x, c0, c1, c2, c3, c4, c5, c6, c7);
        r.y = horner8(x.y, c0, c1, c2, c3, c4, c5, c6, c7);
        r.z = horner8(x.z, c0, c1, c2, c3, c4, c5, c6, c7);
        r.w = horner8(x.w, c0, c1, c2, c3, c4, c5, c6, c7);
        out[i] = r;
    }
}

extern "C" void kernel_launch(void* const* d_in, const int* in_sizes, int n_in,
                              void* d_out, int out_size, void* d_ws, size_t ws_size,
                              hipStream_t stream) {
    const f32x4* X = (const f32x4*)d_in[0];
    const float* w = (const float*)d_in[1];
    const float* b = (const float*)d_in[2];
    f32x4* out = (f32x4*)d_out;

    const int n = in_sizes[0];        // 8388608
    const int n4 = n / 4;             // 2097152

    const int block = 256;
    const int threads_needed = n4 / UNROLL;

    if ((n % 4 == 0) && (n4 % (block * UNROLL) == 0)) {
        const int grid = threads_needed / block;   // 2048 for N=8388608
        PolyModel_poly_fast<<<grid, block, 0, stream>>>(X, w, b, out, threads_needed);
    } else {
        int grid = (n4 + block - 1) / block;
        if (grid > 2048) grid = 2048;
        PolyModel_poly_generic<<<grid, block, 0, stream>>>(X, w, b, out, n4);
    }
}

// Round 4
// 15.978 us; speedup vs baseline: 1.0007x; 1.0007x over previous
//
#include <hip/hip_runtime.h>
#include <hip/hip_bf16.h>

// out[i] = b + sum_{k=0..7} (w[k]/k!) * X[i]^k   — Horner, float4-vectorized.
// Memory-bound: 67.1 MB total traffic at N=8388608 → ~10.5 us floor @ 6.3 TB/s
// (m13 copy ceiling). Falsification config: UNROLL=8 (128 B/thread in flight),
// 1024 blocks x 256 threads, cached (non-NT) loads/stores.

typedef float f32x4 __attribute__((ext_vector_type(4)));

#define UNROLL 8

__device__ __forceinline__ float horner8(float x, float c0, float c1, float c2,
                                         float c3, float c4, float c5, float c6,
                                         float c7) {
    float r = fmaf(c7, x, c6);
    r = fmaf(r, x, c5);
    r = fmaf(r, x, c4);
    r = fmaf(r, x, c3);
    r = fmaf(r, x, c2);
    r = fmaf(r, x, c1);
    r = fmaf(r, x, c0);
    return r;
}

__global__ __launch_bounds__(256) void PolyModel_poly_fast(
    const f32x4* __restrict__ X,
    const float* __restrict__ w,
    const float* __restrict__ b,
    f32x4* __restrict__ out,
    int stride)   // threads in grid = n4 / UNROLL
{
    const float c0 = w[0] + b[0];
    const float c1 = w[1];
    const float c2 = w[2] * 0.5f;
    const float c3 = w[3] * (1.0f / 6.0f);
    const float c4 = w[4] * (1.0f / 24.0f);
    const float c5 = w[5] * (1.0f / 120.0f);
    const float c6 = w[6] * (1.0f / 720.0f);
    const float c7 = w[7] * (1.0f / 5040.0f);

    const int tid = blockIdx.x * blockDim.x + threadIdx.x;

    f32x4 x[UNROLL];
#pragma unroll
    for (int u = 0; u < UNROLL; ++u)
        x[u] = X[tid + u * stride];

#pragma unroll
    for (int u = 0; u < UNROLL; ++u) {
        f32x4 r;
        r.x = horner8(x[u].x, c0, c1, c2, c3, c4, c5, c6, c7);
        r.y = horner8(x[u].y, c0, c1, c2, c3, c4, c5, c6, c7);
        r.z = horner8(x[u].z, c0, c1, c2, c3, c4, c5, c6, c7);
        r.w = horner8(x[u].w, c0, c1, c2, c3, c4, c5, c6, c7);
        out[tid + u * stride] = r;
    }
}

// Generic fallback (any n divisible by 4) — grid-stride Horner.
__global__ __launch_bounds__(256) void PolyModel_poly_generic(
    const f32x4* __restrict__ X,
    const float* __restrict__ w,
    const float* __restrict__ b,
    f32x4* __restrict__ out,
    int n4)
{
    const float c0 = w[0] + b[0];
    const float c1 = w[1];
    const float c2 = w[2] * 0.5f;
    const float c3 = w[3] * (1.0f / 6.0f);
    const float c4 = w[4] * (1.0f / 24.0f);
    const float c5 = w[5] * (1.0f / 120.0f);
    const float c6 = w[6] * (1.0f / 720.0f);
    const float c7 = w[7] * (1.0f / 5040.0f);

    const int stride = gridDim.x * blockDim.x;
    for (int i = blockIdx.x * blockDim.x + threadIdx.x; i < n4; i += stride) {
        f32x4 x = X[i];
        f32x4 r;
        r.x = horner8(x.x, c0, c1, c2, c3, c4, c5, c6, c7);
        r.y = horner8(x.y, c0, c1, c2, c3, c4, c5, c6, c7);
        r.z = horner8(x.z, c0, c1, c2, c3, c4, c5, c6, c7);
        r.w = horner8(x.w, c0, c1, c2, c3, c4, c5, c6, c7);
        out[i] = r;
    }
}

extern "C" void kernel_launch(void* const* d_in, const int* in_sizes, int n_in,
                              void* d_out, int out_size, void* d_ws, size_t ws_size,
                              hipStream_t stream) {
    const f32x4* X = (const f32x4*)d_in[0];
    const float* w = (const float*)d_in[1];
    const float* b = (const float*)d_in[2];
    f32x4* out = (f32x4*)d_out;

    const int n = in_sizes[0];        // 8388608
    const int n4 = n / 4;             // 2097152

    const int block = 256;
    const int threads_needed = n4 / UNROLL;

    if ((n % 4 == 0) && (n4 % (block * UNROLL) == 0)) {
        const int grid = threads_needed / block;   // 1024 for N=8388608
        PolyModel_poly_fast<<<grid, block, 0, stream>>>(X, w, b, out, threads_needed);
    } else {
        int grid = (n4 + block - 1) / block;
        if (grid > 2048) grid = 2048;
        PolyModel_poly_generic<<<grid, block, 0, stream>>>(X, w, b, out, n4);
    }
}